// Round 10
// baseline (113.532 us; speedup 1.0000x reference)
//
#include <hip/hip_runtime.h>
#include <hip/hip_bf16.h>

#define NB 2
#define ND 1024
#define NL 4096
#define NFS 4
#define NDEPTH 11
#define LN_EPS 1e-5f

#define BM 128
#define BN 128
#define BK 32
#define NKI (ND / BK)
#define ASZ (BM * BK)  // shorts per A (or B) buffer

#define CPAD 3072          // f16 elements of zero pad (lev10 reads back 3*1024)
#define CBUF (CPAD + NL)   // 7168 f16 = 14336 B per row buffer

typedef __bf16 bf16x8 __attribute__((ext_vector_type(8)));
typedef float f32x4 __attribute__((ext_vector_type(4)));
typedef _Float16 half8 __attribute__((ext_vector_type(8)));

__device__ __forceinline__ unsigned short f2bf(float f) {
    __hip_bfloat16 h = __float2bfloat16(f);
    unsigned short u;
    __builtin_memcpy(&u, &h, 2);
    return u;
}

__device__ __forceinline__ float bf2f(unsigned short u) {
    unsigned int ui = (unsigned int)u << 16;
    float f;
    __builtin_memcpy(&f, &ui, 4);
    return f;
}

__device__ __forceinline__ unsigned int pack2bf(float lo, float hi) {
    return (unsigned int)f2bf(lo) | ((unsigned int)f2bf(hi) << 16);
}

// fast sigmoid: v_exp + raw v_rcp (avoids IEEE div sequence)
__device__ __forceinline__ float sigm(float v) {
    return __builtin_amdgcn_rcpf(1.f + __expf(-v));
}

// async global->LDS, 16B per lane (wave-uniform LDS base + lane*16)
__device__ __forceinline__ void llds16(const void* g, void* l) {
    __builtin_amdgcn_global_load_lds(
        (const __attribute__((address_space(1))) unsigned int*)g,
        (__attribute__((address_space(3))) unsigned int*)l, 16, 0, 0);
}

// ---------------------------------------------------------------- K0: W -> bf16
__global__ __launch_bounds__(256) void wconv_kernel(const float* __restrict__ w,
                                                    unsigned short* __restrict__ wbf) {
    const int idx8 = (blockIdx.x * 256 + threadIdx.x) * 8;
    const float4 v0 = *reinterpret_cast<const float4*>(w + idx8);
    const float4 v1 = *reinterpret_cast<const float4*>(w + idx8 + 4);
    uint4 o;
    o.x = pack2bf(v0.x, v0.y);
    o.y = pack2bf(v0.z, v0.w);
    o.z = pack2bf(v1.x, v1.y);
    o.w = pack2bf(v1.z, v1.w);
    *reinterpret_cast<uint4*>(wbf + idx8) = o;
}

// ------------------------------------------------- K1: dilated conv cascade + gating
// TWO rows per block (b=0 and b=1 of channel d: same filters). 512 threads; thread t
// owns positions [t*8, t*8+8) of BOTH rows as half8 states. f16 LDS buffers (one per
// row, 3072-elem zero pad each, in-place update, 2 barriers/level — but each barrier
// now serves 2 rows of work). Conv math is packed v_pk_fma_f16; taps for dil>=8 are
// single aligned ds_read_b128; dil=1,2,4 static shufflevector mixes. Gate stays f32.
__global__ __launch_bounds__(512, 8) void conv_cascade_kernel(const float* __restrict__ x,
                                                              const float* __restrict__ h0,
                                                              const float* __restrict__ h1,
                                                              unsigned short* __restrict__ ybf) {
    __shared__ _Float16 a_sh[2][CBUF];  // 28672 B
    const int d = blockIdx.x;           // channel
    const int t = threadIdx.x;

    // zero the pads (never written again)
    if (t < CPAD / 8) {
        *reinterpret_cast<half8*>(&a_sh[0][t * 8]) = (half8)0;
        *reinterpret_cast<half8*>(&a_sh[1][t * 8]) = (half8)0;
    }

    const float* xrow0 = x + (size_t)d * NL;
    const float* xrow1 = x + (size_t)(ND + d) * NL;

    _Float16 h0c[NFS], h1c[NFS];
#pragma unroll
    for (int k = 0; k < NFS; ++k) {
        h0c[k] = (_Float16)h0[d * NFS + k];
        h1c[k] = (_Float16)h1[d * NFS + k];
    }

    const int A = CPAD + t * 8;
    half8 cur0, cur1;
    {
        const float4 v0 = *reinterpret_cast<const float4*>(xrow0 + t * 8);
        const float4 v1 = *reinterpret_cast<const float4*>(xrow0 + t * 8 + 4);
        cur0[0] = (_Float16)v0.x; cur0[1] = (_Float16)v0.y;
        cur0[2] = (_Float16)v0.z; cur0[3] = (_Float16)v0.w;
        cur0[4] = (_Float16)v1.x; cur0[5] = (_Float16)v1.y;
        cur0[6] = (_Float16)v1.z; cur0[7] = (_Float16)v1.w;
        const float4 w0 = *reinterpret_cast<const float4*>(xrow1 + t * 8);
        const float4 w1 = *reinterpret_cast<const float4*>(xrow1 + t * 8 + 4);
        cur1[0] = (_Float16)w0.x; cur1[1] = (_Float16)w0.y;
        cur1[2] = (_Float16)w0.z; cur1[3] = (_Float16)w0.w;
        cur1[4] = (_Float16)w1.x; cur1[5] = (_Float16)w1.y;
        cur1[6] = (_Float16)w1.z; cur1[7] = (_Float16)w1.w;
    }
    *reinterpret_cast<half8*>(&a_sh[0][A]) = cur0;
    *reinterpret_cast<half8*>(&a_sh[1][A]) = cur1;

    float yacc0[8], yacc1[8];
    half8 bprev0 = (half8)0, bprev1 = (half8)0;
#pragma unroll
    for (int j = 0; j < 8; ++j) { yacc0[j] = 0.f; yacc1[j] = 0.f; }
    __syncthreads();

    half8 an0, bn0, an1, bn1;

#define CMATH(cur, a1, a2, a3, an, bn)                                \
    an = (cur)*h0c[3] + (a1)*h0c[2] + (a2)*h0c[1] + (a3)*h0c[0];      \
    bn = (cur)*h1c[3] + (a1)*h1c[2] + (a2)*h1c[1] + (a3)*h1c[0];

#define CFIN(r, an, bn, cur, bprev, yacc, SC)                         \
    {                                                                 \
        *reinterpret_cast<half8*>(&a_sh[r][A]) = an;                  \
        if ((SC) > 0.f) {                                             \
            _Pragma("unroll") for (int j = 0; j < 8; ++j)             \
                yacc[j] += (SC)*sigm((float)an[j]) * (float)bprev[j]; \
        }                                                             \
        cur = an;                                                     \
        bprev = bn;                                                   \
    }

    // ---- lev 0 (dil=1)
    {
        const half8 m0 = *reinterpret_cast<const half8*>(&a_sh[0][A - 8]);
        const half8 m1 = *reinterpret_cast<const half8*>(&a_sh[1][A - 8]);
        {
            const half8 a1 = __builtin_shufflevector(m0, cur0, 7, 8, 9, 10, 11, 12, 13, 14);
            const half8 a2 = __builtin_shufflevector(m0, cur0, 6, 7, 8, 9, 10, 11, 12, 13);
            const half8 a3 = __builtin_shufflevector(m0, cur0, 5, 6, 7, 8, 9, 10, 11, 12);
            CMATH(cur0, a1, a2, a3, an0, bn0)
        }
        {
            const half8 a1 = __builtin_shufflevector(m1, cur1, 7, 8, 9, 10, 11, 12, 13, 14);
            const half8 a2 = __builtin_shufflevector(m1, cur1, 6, 7, 8, 9, 10, 11, 12, 13);
            const half8 a3 = __builtin_shufflevector(m1, cur1, 5, 6, 7, 8, 9, 10, 11, 12);
            CMATH(cur1, a1, a2, a3, an1, bn1)
        }
        __syncthreads();
        CFIN(0, an0, bn0, cur0, bprev0, yacc0, 0.f)
        CFIN(1, an1, bn1, cur1, bprev1, yacc1, 0.f)
        __syncthreads();
    }

    // ---- lev 1 (dil=2): gate x2
    {
        const half8 m0 = *reinterpret_cast<const half8*>(&a_sh[0][A - 8]);
        const half8 m1 = *reinterpret_cast<const half8*>(&a_sh[1][A - 8]);
        {
            const half8 a1 = __builtin_shufflevector(m0, cur0, 6, 7, 8, 9, 10, 11, 12, 13);
            const half8 a2 = __builtin_shufflevector(m0, cur0, 4, 5, 6, 7, 8, 9, 10, 11);
            const half8 a3 = __builtin_shufflevector(m0, cur0, 2, 3, 4, 5, 6, 7, 8, 9);
            CMATH(cur0, a1, a2, a3, an0, bn0)
        }
        {
            const half8 a1 = __builtin_shufflevector(m1, cur1, 6, 7, 8, 9, 10, 11, 12, 13);
            const half8 a2 = __builtin_shufflevector(m1, cur1, 4, 5, 6, 7, 8, 9, 10, 11);
            const half8 a3 = __builtin_shufflevector(m1, cur1, 2, 3, 4, 5, 6, 7, 8, 9);
            CMATH(cur1, a1, a2, a3, an1, bn1)
        }
        __syncthreads();
        CFIN(0, an0, bn0, cur0, bprev0, yacc0, 2.f)
        CFIN(1, an1, bn1, cur1, bprev1, yacc1, 2.f)
        __syncthreads();
    }

    // ---- lev 2 (dil=4)
    {
        const half8 m0 = *reinterpret_cast<const half8*>(&a_sh[0][A - 8]);
        const half8 p0 = *reinterpret_cast<const half8*>(&a_sh[0][A - 16]);
        const half8 m1 = *reinterpret_cast<const half8*>(&a_sh[1][A - 8]);
        const half8 p1 = *reinterpret_cast<const half8*>(&a_sh[1][A - 16]);
        {
            const half8 a1 = __builtin_shufflevector(m0, cur0, 4, 5, 6, 7, 8, 9, 10, 11);
            const half8 a3 = __builtin_shufflevector(p0, m0, 4, 5, 6, 7, 8, 9, 10, 11);
            CMATH(cur0, a1, m0, a3, an0, bn0)
        }
        {
            const half8 a1 = __builtin_shufflevector(m1, cur1, 4, 5, 6, 7, 8, 9, 10, 11);
            const half8 a3 = __builtin_shufflevector(p1, m1, 4, 5, 6, 7, 8, 9, 10, 11);
            CMATH(cur1, a1, m1, a3, an1, bn1)
        }
        __syncthreads();
        CFIN(0, an0, bn0, cur0, bprev0, yacc0, 1.f)
        CFIN(1, an1, bn1, cur1, bprev1, yacc1, 1.f)
        __syncthreads();
    }

    // ---- lev 3..9 (dil=8..512): direct aligned half8 reads
    int dil = 8;
#pragma unroll 1
    for (int lev = 3; lev <= 9; ++lev) {
        {
            const half8 a1 = *reinterpret_cast<const half8*>(&a_sh[0][A - dil]);
            const half8 a2 = *reinterpret_cast<const half8*>(&a_sh[0][A - 2 * dil]);
            const half8 a3 = *reinterpret_cast<const half8*>(&a_sh[0][A - 3 * dil]);
            CMATH(cur0, a1, a2, a3, an0, bn0)
        }
        {
            const half8 a1 = *reinterpret_cast<const half8*>(&a_sh[1][A - dil]);
            const half8 a2 = *reinterpret_cast<const half8*>(&a_sh[1][A - 2 * dil]);
            const half8 a3 = *reinterpret_cast<const half8*>(&a_sh[1][A - 3 * dil]);
            CMATH(cur1, a1, a2, a3, an1, bn1)
        }
        __syncthreads();
        CFIN(0, an0, bn0, cur0, bprev0, yacc0, 1.f)
        CFIN(1, an1, bn1, cur1, bprev1, yacc1, 1.f)
        dil <<= 1;
        __syncthreads();
    }

    // ---- lev 10 (dil=1024): a-conv only (b_list[10] dead), no write-back
    {
        const half8 a1 = *reinterpret_cast<const half8*>(&a_sh[0][A - 1024]);
        const half8 a2 = *reinterpret_cast<const half8*>(&a_sh[0][A - 2048]);
        const half8 a3 = *reinterpret_cast<const half8*>(&a_sh[0][A - 3072]);
        an0 = cur0 * h0c[3] + a1 * h0c[2] + a2 * h0c[1] + a3 * h0c[0];
        const half8 c1 = *reinterpret_cast<const half8*>(&a_sh[1][A - 1024]);
        const half8 c2 = *reinterpret_cast<const half8*>(&a_sh[1][A - 2048]);
        const half8 c3 = *reinterpret_cast<const half8*>(&a_sh[1][A - 3072]);
        an1 = cur1 * h0c[3] + c1 * h0c[2] + c2 * h0c[1] + c3 * h0c[0];
#pragma unroll
        for (int j = 0; j < 8; ++j) {
            yacc0[j] += sigm((float)an0[j]) * (float)bprev0[j];
            yacc1[j] += sigm((float)an1[j]) * (float)bprev1[j];
        }
    }
#undef CMATH
#undef CFIN

    uint4 o;
    o.x = pack2bf(yacc0[0], yacc0[1]);
    o.y = pack2bf(yacc0[2], yacc0[3]);
    o.z = pack2bf(yacc0[4], yacc0[5]);
    o.w = pack2bf(yacc0[6], yacc0[7]);
    *reinterpret_cast<uint4*>(ybf + (size_t)d * NL + t * 8) = o;
    o.x = pack2bf(yacc1[0], yacc1[1]);
    o.y = pack2bf(yacc1[2], yacc1[3]);
    o.z = pack2bf(yacc1[4], yacc1[5]);
    o.w = pack2bf(yacc1[6], yacc1[7]);
    *reinterpret_cast<uint4*>(ybf + (size_t)(ND + d) * NL + t * 8) = o;
}

// ------------------------------------------- K2: y [b][c][l] bf16 -> yT [b][l][c] bf16
__global__ __launch_bounds__(256) void transpose_kernel(const unsigned short* __restrict__ ybf,
                                                        unsigned short* __restrict__ yT) {
    __shared__ unsigned short tile[64][66];
    const int l0 = blockIdx.x * 64;
    const int c0 = blockIdx.y * 64;
    const int b = blockIdx.z;
    const int t = threadIdx.x;
    const int li = t & 63, cg = t >> 6;
#pragma unroll
    for (int k = 0; k < 16; ++k) {
        const int ci = cg * 16 + k;
        tile[ci][li] = ybf[(size_t)(b * ND + c0 + ci) * NL + l0 + li];
    }
    __syncthreads();
    const int ci2 = t & 63, lg = t >> 6;
#pragma unroll
    for (int k = 0; k < 16; ++k) {
        const int li2 = lg * 16 + k;
        yT[((size_t)b * NL + l0 + li2) * ND + c0 + ci2] = tile[ci2][li2];
    }
}

// --------------------------- K3: mixed[b][o][l] = bf16( (W @ y)[o][l] + b_mix[o] )
// ring-3 LDS staging, counted vmcnt(4); XCD-chunked block swizzle: each XCD's 64
// contiguous wgids = 4 n-panels x 8 m x 2 b -> yT panels reused 8x within one L2.
__global__ __launch_bounds__(256) void gemm_kernel(const unsigned short* __restrict__ wbf,
                                                   const unsigned short* __restrict__ yT,
                                                   const float* __restrict__ bmix,
                                                   unsigned short* __restrict__ mixed) {
    __shared__ unsigned short As[3][BM][BK];  // 24 KiB
    __shared__ unsigned short Bs[3][BN][BK];  // 24 KiB

    // XCD swizzle: 512 blocks, 8 XCDs, 64 per XCD (512%8==0 -> bijective)
    const int orig = blockIdx.x;
    const int wgid = (orig & 7) * 64 + (orig >> 3);
    const int b = wgid & 1;
    const int m0 = ((wgid >> 1) & 7) * BM;
    const int n0 = (wgid >> 4) * BN;

    const int t = threadIdx.x;
    const int lane = t & 63, wid = t >> 6;
    const int wr = wid >> 1, wc = wid & 1;  // 2x2 waves, each 64x64
    const int fr = lane & 15;
    const int fk = (lane >> 4) * 8;

    const int srow = wid * 32 + (lane >> 2);
    const int sk = (lane & 3) * 8;
    const unsigned short* Ag = wbf + (size_t)(m0 + srow) * ND + sk;
    const unsigned short* Bg = yT + ((size_t)b * NL + n0 + srow) * ND + sk;
    unsigned short* A0 = &As[0][0][0];
    unsigned short* B0 = &Bs[0][0][0];
    unsigned short* AsW = A0 + wid * 32 * BK;
    unsigned short* BsW = B0 + wid * 32 * BK;

#define STAGE(bo, kt)                           \
    llds16(Ag + (kt), AsW + (bo));              \
    llds16(Ag + (kt) + 16 * ND, AsW + (bo) + 16 * BK); \
    llds16(Bg + (kt), BsW + (bo));              \
    llds16(Bg + (kt) + 16 * ND, BsW + (bo) + 16 * BK);

    f32x4 acc[4][4];
#pragma unroll
    for (int mi = 0; mi < 4; ++mi)
#pragma unroll
        for (int ni = 0; ni < 4; ++ni)
            acc[mi][ni] = (f32x4){0.f, 0.f, 0.f, 0.f};

    // prologue: stage tiles 0,1 into bufs 0,1 (8 loads outstanding)
    STAGE(0, 0)
    STAGE(ASZ, BK)

    int bc = 0;   // compute buffer index
    int bs = 2;   // stage buffer index
#pragma unroll 1
    for (int ki = 0; ki < NKI; ++ki) {
        if (ki + 1 < NKI) {
            asm volatile("s_waitcnt vmcnt(4)" ::: "memory");  // tile ki landed
        } else {
            asm volatile("s_waitcnt vmcnt(0)" ::: "memory");
        }
        __builtin_amdgcn_s_barrier();
        __builtin_amdgcn_sched_barrier(0);

        if (ki + 2 < NKI) {
            const int bo = bs * ASZ;
            const int kt = (ki + 2) * BK;
            STAGE(bo, kt)
        }

        const int bco = bc * ASZ;
        bf16x8 af[4], bv[4];
#pragma unroll
        for (int mi = 0; mi < 4; ++mi)
            af[mi] = *reinterpret_cast<const bf16x8*>(A0 + bco + (wr * 64 + mi * 16 + fr) * BK + fk);
#pragma unroll
        for (int ni = 0; ni < 4; ++ni)
            bv[ni] = *reinterpret_cast<const bf16x8*>(B0 + bco + (wc * 64 + ni * 16 + fr) * BK + fk);
#pragma unroll
        for (int mi = 0; mi < 4; ++mi)
#pragma unroll
            for (int ni = 0; ni < 4; ++ni)
                acc[mi][ni] = __builtin_amdgcn_mfma_f32_16x16x32_bf16(af[mi], bv[ni],
                                                                      acc[mi][ni], 0, 0, 0);
        bc = (bc == 2) ? 0 : bc + 1;
        bs = (bs == 2) ? 0 : bs + 1;
    }
#undef STAGE

    // epilogue: D[row][col], col = lane&15, row = (lane>>4)*4 + r
    const size_t bbase = (size_t)b * ND * NL;
#pragma unroll
    for (int mi = 0; mi < 4; ++mi) {
#pragma unroll
        for (int r = 0; r < 4; ++r) {
            const int o = m0 + wr * 64 + mi * 16 + (lane >> 4) * 4 + r;
            const float bm = bmix[o];
            const size_t rowbase = bbase + (size_t)o * NL;
#pragma unroll
            for (int ni = 0; ni < 4; ++ni) {
                const int l = n0 + wc * 64 + ni * 16 + fr;
                mixed[rowbase + l] = f2bf(acc[mi][ni][r] + bm);
            }
        }
    }
}

// ------------------------- K4: z = mixed + x (regs) -> LayerNorm over channels -> out
__global__ __launch_bounds__(512) void ln_kernel(const unsigned short* __restrict__ mixed,
                                                 const float* __restrict__ x,
                                                 const float* __restrict__ gamma,
                                                 const float* __restrict__ beta,
                                                 float* __restrict__ out) {
    const int b = blockIdx.y;
    const int l0 = blockIdx.x * 32;
    const int tl = threadIdx.x & 31, tg = threadIdx.x >> 5;  // 16 c-groups x 32 cols
    const size_t base = (size_t)b * ND * NL + l0 + tl;

    float zv[64];
    float s = 0.f, q = 0.f;
#pragma unroll
    for (int j = 0; j < 64; ++j) {
        const size_t idx = base + (size_t)(tg + j * 16) * NL;
        const float v = bf2f(mixed[idx]) + x[idx];
        zv[j] = v;
        s += v;
        q += v * v;
    }

    __shared__ float sred[16][33], qred[16][33];
    __shared__ float mu_s[32], rs_s[32];
    sred[tg][tl] = s;
    qred[tg][tl] = q;
    __syncthreads();
    if (tg == 0) {
        float S = 0.f, Q = 0.f;
#pragma unroll
        for (int g = 0; g < 16; ++g) {
            S += sred[g][tl];
            Q += qred[g][tl];
        }
        const float mu = S * (1.f / ND);
        const float var = Q * (1.f / ND) - mu * mu;
        mu_s[tl] = mu;
        rs_s[tl] = rsqrtf(var + LN_EPS);
    }
    __syncthreads();
    const float mu = mu_s[tl], rs = rs_s[tl];
#pragma unroll
    for (int j = 0; j < 64; ++j) {
        const int c = tg + j * 16;
        out[base + (size_t)c * NL] = (zv[j] - mu) * rs * gamma[c] + beta[c];
    }
}

extern "C" void kernel_launch(void* const* d_in, const int* in_sizes, int n_in,
                              void* d_out, int out_size, void* d_ws, size_t ws_size,
                              hipStream_t stream) {
    (void)in_sizes; (void)n_in; (void)out_size; (void)ws_size;
    const float* x = (const float*)d_in[0];
    const float* h0 = (const float*)d_in[1];
    const float* h1 = (const float*)d_in[2];
    const float* wmix = (const float*)d_in[3];
    const float* bmix = (const float*)d_in[4];
    const float* gamma = (const float*)d_in[5];
    const float* beta = (const float*)d_in[6];
    float* out = (float*)d_out;

    char* ws = (char*)d_ws;
    unsigned short* ybf = (unsigned short*)(ws);                              // 16 MiB
    unsigned short* yT = (unsigned short*)(ws + (size_t)16 * 1024 * 1024);    // 16 MiB
    unsigned short* wbf = (unsigned short*)(ws + (size_t)32 * 1024 * 1024);   // 2 MiB
    unsigned short* mixed = (unsigned short*)(ws + (size_t)34 * 1024 * 1024); // 16 MiB

    wconv_kernel<<<dim3(ND * ND / (256 * 8)), 256, 0, stream>>>(wmix, wbf);
    conv_cascade_kernel<<<dim3(ND), 512, 0, stream>>>(x, h0, h1, ybf);
    transpose_kernel<<<dim3(NL / 64, ND / 64, NB), 256, 0, stream>>>(ybf, yT);
    gemm_kernel<<<dim3(512), 256, 0, stream>>>(wbf, yT, bmix, mixed);
    ln_kernel<<<dim3(NL / 32, NB), 512, 0, stream>>>(mixed, x, gamma, beta, out);
}

// Round 11
// 99.980 us; speedup vs baseline: 1.1355x; 1.1355x over previous
//
#include <hip/hip_runtime.h>
#include <hip/hip_bf16.h>
#include <hip/hip_fp16.h>

#define NB 2
#define ND 1024
#define NL 4096
#define NFS 4
#define NDEPTH 11
#define LN_EPS 1e-5f

#define BM 128
#define BN 128
#define BK 32
#define NKI (ND / BK)
#define ASZ (BM * BK)  // shorts per A (or B) buffer

#define CPAD 3072          // f16 elements of zero pad (lev10 reads back 3*1024)
#define CBUF (CPAD + NL)   // 7168 f16 = 14336 B per buffer

typedef __bf16 bf16x8 __attribute__((ext_vector_type(8)));
typedef float f32x4 __attribute__((ext_vector_type(4)));
typedef _Float16 half8 __attribute__((ext_vector_type(8)));

__device__ __forceinline__ unsigned short f2bf(float f) {
    __hip_bfloat16 h = __float2bfloat16(f);
    unsigned short u;
    __builtin_memcpy(&u, &h, 2);
    return u;
}

__device__ __forceinline__ float bf2f(unsigned short u) {
    unsigned int ui = (unsigned int)u << 16;
    float f;
    __builtin_memcpy(&f, &ui, 4);
    return f;
}

__device__ __forceinline__ unsigned int pack2bf(float lo, float hi) {
    return (unsigned int)f2bf(lo) | ((unsigned int)f2bf(hi) << 16);
}

// async global->LDS, 16B per lane (wave-uniform LDS base + lane*16)
__device__ __forceinline__ void llds16(const void* g, void* l) {
    __builtin_amdgcn_global_load_lds(
        (const __attribute__((address_space(1))) unsigned int*)g,
        (__attribute__((address_space(3))) unsigned int*)l, 16, 0, 0);
}

// ---------------------------------------------------------------- K0: W -> bf16
__global__ __launch_bounds__(256) void wconv_kernel(const float* __restrict__ w,
                                                    unsigned short* __restrict__ wbf) {
    const int idx8 = (blockIdx.x * 256 + threadIdx.x) * 8;
    const float4 v0 = *reinterpret_cast<const float4*>(w + idx8);
    const float4 v1 = *reinterpret_cast<const float4*>(w + idx8 + 4);
    uint4 o;
    o.x = pack2bf(v0.x, v0.y);
    o.y = pack2bf(v0.z, v0.w);
    o.z = pack2bf(v1.x, v1.y);
    o.w = pack2bf(v1.z, v1.w);
    *reinterpret_cast<uint4*>(wbf + idx8) = o;
}

// ------------------------------------------------- K1: dilated conv cascade + gating
// Single row per block (R9 structure), 512 threads, thread t owns [t*8, t*8+8) as a
// half8. Conv math: packed v_pk_fma_f16. GATE fully f16-packed: sigma(a)*b via
// h2exp2 / h2rcp / __hfma2 on __half2 pairs, yacc accumulated as 4x __half2 (this
// removes the f32 converts + IEEE f32 trans that dominated VALU issue R5-R10).
// Double-buffered LDS (pointer swap) -> ONE barrier per level.
__global__ __launch_bounds__(512, 8) void conv_cascade_kernel(const float* __restrict__ x,
                                                              const float* __restrict__ h0,
                                                              const float* __restrict__ h1,
                                                              unsigned short* __restrict__ ybf) {
    __shared__ _Float16 a_sh[2][CBUF];  // 28672 B
    const int row = blockIdx.x;         // b*ND + d
    const int d = row & (ND - 1);
    const int t = threadIdx.x;

    // zero both pads (never written again)
    if (t < CPAD / 8) {
        *reinterpret_cast<half8*>(&a_sh[0][t * 8]) = (half8)0;
        *reinterpret_cast<half8*>(&a_sh[1][t * 8]) = (half8)0;
    }

    const float* xrow = x + (size_t)row * NL;

    _Float16 h0c[NFS], h1c[NFS];
#pragma unroll
    for (int k = 0; k < NFS; ++k) {
        h0c[k] = (_Float16)h0[d * NFS + k];
        h1c[k] = (_Float16)h1[d * NFS + k];
    }

    const int A = CPAD + t * 8;
    half8 cur;
    {
        const float4 v0 = *reinterpret_cast<const float4*>(xrow + t * 8);
        const float4 v1 = *reinterpret_cast<const float4*>(xrow + t * 8 + 4);
        cur[0] = (_Float16)v0.x; cur[1] = (_Float16)v0.y;
        cur[2] = (_Float16)v0.z; cur[3] = (_Float16)v0.w;
        cur[4] = (_Float16)v1.x; cur[5] = (_Float16)v1.y;
        cur[6] = (_Float16)v1.z; cur[7] = (_Float16)v1.w;
    }
    _Float16* rbp = &a_sh[0][0];
    _Float16* wbp = &a_sh[1][0];
    *reinterpret_cast<half8*>(&rbp[A]) = cur;

    const __half2 nlog2e = __float2half2_rn(-1.44269504f);
    const __half2 one2 = __float2half2_rn(1.f);
    const __half2 two2 = __float2half2_rn(2.f);
    __half2 yacc2[4];
#pragma unroll
    for (int p = 0; p < 4; ++p) yacc2[p] = __float2half2_rn(0.f);
    half8 bprev = (half8)0;
    __syncthreads();

    half8 an, bn;

#define CMATH(a1, a2, a3)                                           \
    an = cur * h0c[3] + (a1)*h0c[2] + (a2)*h0c[1] + (a3)*h0c[0];    \
    bn = cur * h1c[3] + (a1)*h1c[2] + (a2)*h1c[1] + (a3)*h1c[0];

// yacc += SC2 * sigmoid(an) * bprev, fully packed f16
#define GATE(SC2)                                                   \
    {                                                               \
        __half2 ap[4], bp[4];                                       \
        __builtin_memcpy(ap, &an, 16);                              \
        __builtin_memcpy(bp, &bprev, 16);                           \
        _Pragma("unroll") for (int p = 0; p < 4; ++p) {             \
            const __half2 e = h2exp2(__hmul2(ap[p], nlog2e));       \
            const __half2 s = h2rcp(__hadd2(e, one2));              \
            const __half2 g = __hmul2(__hmul2(s, bp[p]), SC2);      \
            yacc2[p] = __hadd2(g, yacc2[p]);                        \
        }                                                           \
    }

// write-back to wbp + state update + buffer swap (single barrier after)
#define CFIN()                                                      \
    {                                                               \
        *reinterpret_cast<half8*>(&wbp[A]) = an;                    \
        cur = an;                                                   \
        bprev = bn;                                                 \
        _Float16* tmpp = rbp; rbp = wbp; wbp = tmpp;                \
    }

    // ---- lev 0 (dil=1): static shifts, no gate
    {
        const half8 m = *reinterpret_cast<const half8*>(&rbp[A - 8]);
        const half8 a1 = __builtin_shufflevector(m, cur, 7, 8, 9, 10, 11, 12, 13, 14);
        const half8 a2 = __builtin_shufflevector(m, cur, 6, 7, 8, 9, 10, 11, 12, 13);
        const half8 a3 = __builtin_shufflevector(m, cur, 5, 6, 7, 8, 9, 10, 11, 12);
        CMATH(a1, a2, a3)
        CFIN()
        __syncthreads();
    }

    // ---- lev 1 (dil=2): gate x2
    {
        const half8 m = *reinterpret_cast<const half8*>(&rbp[A - 8]);
        const half8 a1 = __builtin_shufflevector(m, cur, 6, 7, 8, 9, 10, 11, 12, 13);
        const half8 a2 = __builtin_shufflevector(m, cur, 4, 5, 6, 7, 8, 9, 10, 11);
        const half8 a3 = __builtin_shufflevector(m, cur, 2, 3, 4, 5, 6, 7, 8, 9);
        CMATH(a1, a2, a3)
        GATE(two2)
        CFIN()
        __syncthreads();
    }

    // ---- lev 2 (dil=4)
    {
        const half8 m = *reinterpret_cast<const half8*>(&rbp[A - 8]);
        const half8 m2 = *reinterpret_cast<const half8*>(&rbp[A - 16]);
        const half8 a1 = __builtin_shufflevector(m, cur, 4, 5, 6, 7, 8, 9, 10, 11);
        const half8 a3 = __builtin_shufflevector(m2, m, 4, 5, 6, 7, 8, 9, 10, 11);
        CMATH(a1, m, a3)
        GATE(one2)
        CFIN()
        __syncthreads();
    }

    // ---- lev 3..9 (dil=8..512): 3 direct aligned half8 reads
    int dil = 8;
#pragma unroll 1
    for (int lev = 3; lev <= 9; ++lev) {
        const half8 a1 = *reinterpret_cast<const half8*>(&rbp[A - dil]);
        const half8 a2 = *reinterpret_cast<const half8*>(&rbp[A - 2 * dil]);
        const half8 a3 = *reinterpret_cast<const half8*>(&rbp[A - 3 * dil]);
        CMATH(a1, a2, a3)
        GATE(one2)
        CFIN()
        dil <<= 1;
        __syncthreads();
    }

    // ---- lev 10 (dil=1024): a-conv only (b_list[10] dead), no write-back.
    //      rbp holds lev9's output after the last swap+barrier.
    {
        const half8 a1 = *reinterpret_cast<const half8*>(&rbp[A - 1024]);
        const half8 a2 = *reinterpret_cast<const half8*>(&rbp[A - 2048]);
        const half8 a3 = *reinterpret_cast<const half8*>(&rbp[A - 3072]);
        an = cur * h0c[3] + a1 * h0c[2] + a2 * h0c[1] + a3 * h0c[0];
        GATE(one2)
    }
#undef CMATH
#undef GATE
#undef CFIN

    const float2 f0 = __half22float2(yacc2[0]);
    const float2 f1 = __half22float2(yacc2[1]);
    const float2 f2 = __half22float2(yacc2[2]);
    const float2 f3 = __half22float2(yacc2[3]);
    uint4 o;
    o.x = pack2bf(f0.x, f0.y);
    o.y = pack2bf(f1.x, f1.y);
    o.z = pack2bf(f2.x, f2.y);
    o.w = pack2bf(f3.x, f3.y);
    *reinterpret_cast<uint4*>(ybf + (size_t)row * NL + t * 8) = o;
}

// ------------------------------------------- K2: y [b][c][l] bf16 -> yT [b][l][c] bf16
__global__ __launch_bounds__(256) void transpose_kernel(const unsigned short* __restrict__ ybf,
                                                        unsigned short* __restrict__ yT) {
    __shared__ unsigned short tile[64][66];
    const int l0 = blockIdx.x * 64;
    const int c0 = blockIdx.y * 64;
    const int b = blockIdx.z;
    const int t = threadIdx.x;
    const int li = t & 63, cg = t >> 6;
#pragma unroll
    for (int k = 0; k < 16; ++k) {
        const int ci = cg * 16 + k;
        tile[ci][li] = ybf[(size_t)(b * ND + c0 + ci) * NL + l0 + li];
    }
    __syncthreads();
    const int ci2 = t & 63, lg = t >> 6;
#pragma unroll
    for (int k = 0; k < 16; ++k) {
        const int li2 = lg * 16 + k;
        yT[((size_t)b * NL + l0 + li2) * ND + c0 + ci2] = tile[ci2][li2];
    }
}

// --------------------------- K3: mixed[b][o][l] = bf16( (W @ y)[o][l] + b_mix[o] )
// ring-3 LDS staging, counted vmcnt(4); XCD-chunked block swizzle.
__global__ __launch_bounds__(256) void gemm_kernel(const unsigned short* __restrict__ wbf,
                                                   const unsigned short* __restrict__ yT,
                                                   const float* __restrict__ bmix,
                                                   unsigned short* __restrict__ mixed) {
    __shared__ unsigned short As[3][BM][BK];  // 24 KiB
    __shared__ unsigned short Bs[3][BN][BK];  // 24 KiB

    // XCD swizzle: 512 blocks, 8 XCDs, 64 per XCD (512%8==0 -> bijective)
    const int orig = blockIdx.x;
    const int wgid = (orig & 7) * 64 + (orig >> 3);
    const int b = wgid & 1;
    const int m0 = ((wgid >> 1) & 7) * BM;
    const int n0 = (wgid >> 4) * BN;

    const int t = threadIdx.x;
    const int lane = t & 63, wid = t >> 6;
    const int wr = wid >> 1, wc = wid & 1;  // 2x2 waves, each 64x64
    const int fr = lane & 15;
    const int fk = (lane >> 4) * 8;

    const int srow = wid * 32 + (lane >> 2);
    const int sk = (lane & 3) * 8;
    const unsigned short* Ag = wbf + (size_t)(m0 + srow) * ND + sk;
    const unsigned short* Bg = yT + ((size_t)b * NL + n0 + srow) * ND + sk;
    unsigned short* A0 = &As[0][0][0];
    unsigned short* B0 = &Bs[0][0][0];
    unsigned short* AsW = A0 + wid * 32 * BK;
    unsigned short* BsW = B0 + wid * 32 * BK;

#define STAGE(bo, kt)                           \
    llds16(Ag + (kt), AsW + (bo));              \
    llds16(Ag + (kt) + 16 * ND, AsW + (bo) + 16 * BK); \
    llds16(Bg + (kt), BsW + (bo));              \
    llds16(Bg + (kt) + 16 * ND, BsW + (bo) + 16 * BK);

    f32x4 acc[4][4];
#pragma unroll
    for (int mi = 0; mi < 4; ++mi)
#pragma unroll
        for (int ni = 0; ni < 4; ++ni)
            acc[mi][ni] = (f32x4){0.f, 0.f, 0.f, 0.f};

    // prologue: stage tiles 0,1 into bufs 0,1 (8 loads outstanding)
    STAGE(0, 0)
    STAGE(ASZ, BK)

    int bc = 0;   // compute buffer index
    int bs = 2;   // stage buffer index
#pragma unroll 1
    for (int ki = 0; ki < NKI; ++ki) {
        if (ki + 1 < NKI) {
            asm volatile("s_waitcnt vmcnt(4)" ::: "memory");  // tile ki landed
        } else {
            asm volatile("s_waitcnt vmcnt(0)" ::: "memory");
        }
        __builtin_amdgcn_s_barrier();
        __builtin_amdgcn_sched_barrier(0);

        if (ki + 2 < NKI) {
            const int bo = bs * ASZ;
            const int kt = (ki + 2) * BK;
            STAGE(bo, kt)
        }

        const int bco = bc * ASZ;
        bf16x8 af[4], bv[4];
#pragma unroll
        for (int mi = 0; mi < 4; ++mi)
            af[mi] = *reinterpret_cast<const bf16x8*>(A0 + bco + (wr * 64 + mi * 16 + fr) * BK + fk);
#pragma unroll
        for (int ni = 0; ni < 4; ++ni)
            bv[ni] = *reinterpret_cast<const bf16x8*>(B0 + bco + (wc * 64 + ni * 16 + fr) * BK + fk);
#pragma unroll
        for (int mi = 0; mi < 4; ++mi)
#pragma unroll
            for (int ni = 0; ni < 4; ++ni)
                acc[mi][ni] = __builtin_amdgcn_mfma_f32_16x16x32_bf16(af[mi], bv[ni],
                                                                      acc[mi][ni], 0, 0, 0);
        bc = (bc == 2) ? 0 : bc + 1;
        bs = (bs == 2) ? 0 : bs + 1;
    }
#undef STAGE

    // epilogue: D[row][col], col = lane&15, row = (lane>>4)*4 + r
    const size_t bbase = (size_t)b * ND * NL;
#pragma unroll
    for (int mi = 0; mi < 4; ++mi) {
#pragma unroll
        for (int r = 0; r < 4; ++r) {
            const int o = m0 + wr * 64 + mi * 16 + (lane >> 4) * 4 + r;
            const float bm = bmix[o];
            const size_t rowbase = bbase + (size_t)o * NL;
#pragma unroll
            for (int ni = 0; ni < 4; ++ni) {
                const int l = n0 + wc * 64 + ni * 16 + fr;
                mixed[rowbase + l] = f2bf(acc[mi][ni][r] + bm);
            }
        }
    }
}

// ------------------------- K4: z = mixed + x (regs) -> LayerNorm over channels -> out
__global__ __launch_bounds__(512) void ln_kernel(const unsigned short* __restrict__ mixed,
                                                 const float* __restrict__ x,
                                                 const float* __restrict__ gamma,
                                                 const float* __restrict__ beta,
                                                 float* __restrict__ out) {
    const int b = blockIdx.y;
    const int l0 = blockIdx.x * 32;
    const int tl = threadIdx.x & 31, tg = threadIdx.x >> 5;  // 16 c-groups x 32 cols
    const size_t base = (size_t)b * ND * NL + l0 + tl;

    float zv[64];
    float s = 0.f, q = 0.f;
#pragma unroll
    for (int j = 0; j < 64; ++j) {
        const size_t idx = base + (size_t)(tg + j * 16) * NL;
        const float v = bf2f(mixed[idx]) + x[idx];
        zv[j] = v;
        s += v;
        q += v * v;
    }

    __shared__ float sred[16][33], qred[16][33];
    __shared__ float mu_s[32], rs_s[32];
    sred[tg][tl] = s;
    qred[tg][tl] = q;
    __syncthreads();
    if (tg == 0) {
        float S = 0.f, Q = 0.f;
#pragma unroll
        for (int g = 0; g < 16; ++g) {
            S += sred[g][tl];
            Q += qred[g][tl];
        }
        const float mu = S * (1.f / ND);
        const float var = Q * (1.f / ND) - mu * mu;
        mu_s[tl] = mu;
        rs_s[tl] = rsqrtf(var + LN_EPS);
    }
    __syncthreads();
    const float mu = mu_s[tl], rs = rs_s[tl];
#pragma unroll
    for (int j = 0; j < 64; ++j) {
        const int c = tg + j * 16;
        out[base + (size_t)c * NL] = (zv[j] - mu) * rs * gamma[c] + beta[c];
    }
}

extern "C" void kernel_launch(void* const* d_in, const int* in_sizes, int n_in,
                              void* d_out, int out_size, void* d_ws, size_t ws_size,
                              hipStream_t stream) {
    (void)in_sizes; (void)n_in; (void)out_size; (void)ws_size;
    const float* x = (const float*)d_in[0];
    const float* h0 = (const float*)d_in[1];
    const float* h1 = (const float*)d_in[2];
    const float* wmix = (const float*)d_in[3];
    const float* bmix = (const float*)d_in[4];
    const float* gamma = (const float*)d_in[5];
    const float* beta = (const float*)d_in[6];
    float* out = (float*)d_out;

    char* ws = (char*)d_ws;
    unsigned short* ybf = (unsigned short*)(ws);                              // 16 MiB
    unsigned short* yT = (unsigned short*)(ws + (size_t)16 * 1024 * 1024);    // 16 MiB
    unsigned short* wbf = (unsigned short*)(ws + (size_t)32 * 1024 * 1024);   // 2 MiB
    unsigned short* mixed = (unsigned short*)(ws + (size_t)34 * 1024 * 1024); // 16 MiB

    wconv_kernel<<<dim3(ND * ND / (256 * 8)), 256, 0, stream>>>(wmix, wbf);
    conv_cascade_kernel<<<dim3(NB * ND), 512, 0, stream>>>(x, h0, h1, ybf);
    transpose_kernel<<<dim3(NL / 64, ND / 64, NB), 256, 0, stream>>>(ybf, yT);
    gemm_kernel<<<dim3(512), 256, 0, stream>>>(wbf, yT, bmix, mixed);
    ln_kernel<<<dim3(NL / 32, NB), 512, 0, stream>>>(mixed, x, gamma, beta, out);
}

// Round 12
// 93.256 us; speedup vs baseline: 1.2174x; 1.0721x over previous
//
#include <hip/hip_runtime.h>
#include <hip/hip_bf16.h>
#include <hip/hip_fp16.h>

#define NB 2
#define ND 1024
#define NL 4096
#define NFS 4
#define NDEPTH 11
#define LN_EPS 1e-5f

#define BM 128
#define BN 128
#define BK 32
#define NKI (ND / BK)
#define ASZ (BM * BK)  // shorts per A (or B) buffer

#define CPAD 3072          // f16 elements of zero pad (lev10 reads back 3*1024)
#define CBUF (CPAD + NL)   // 7168 f16 = 14336 B per buffer

typedef __bf16 bf16x8 __attribute__((ext_vector_type(8)));
typedef float f32x4 __attribute__((ext_vector_type(4)));
typedef _Float16 half8 __attribute__((ext_vector_type(8)));

__device__ __forceinline__ unsigned short f2bf(float f) {
    __hip_bfloat16 h = __float2bfloat16(f);
    unsigned short u;
    __builtin_memcpy(&u, &h, 2);
    return u;
}

__device__ __forceinline__ float bf2f(unsigned short u) {
    unsigned int ui = (unsigned int)u << 16;
    float f;
    __builtin_memcpy(&f, &ui, 4);
    return f;
}

__device__ __forceinline__ unsigned int pack2bf(float lo, float hi) {
    return (unsigned int)f2bf(lo) | ((unsigned int)f2bf(hi) << 16);
}

// async global->LDS, 16B per lane (wave-uniform LDS base + lane*16)
__device__ __forceinline__ void llds16(const void* g, void* l) {
    __builtin_amdgcn_global_load_lds(
        (const __attribute__((address_space(1))) unsigned int*)g,
        (__attribute__((address_space(3))) unsigned int*)l, 16, 0, 0);
}

__device__ __forceinline__ half8 ldx8(const float* p) {
    const float4 v0 = *reinterpret_cast<const float4*>(p);
    const float4 v1 = *reinterpret_cast<const float4*>(p + 4);
    half8 r;
    r[0] = (_Float16)v0.x; r[1] = (_Float16)v0.y;
    r[2] = (_Float16)v0.z; r[3] = (_Float16)v0.w;
    r[4] = (_Float16)v1.x; r[5] = (_Float16)v1.y;
    r[6] = (_Float16)v1.z; r[7] = (_Float16)v1.w;
    return r;
}

// zero-clamped block load: valid address always, result zeroed if off<0
__device__ __forceinline__ half8 ldx8z(const float* xrow, int off) {
    half8 v = ldx8(xrow + (off >= 0 ? off : 0));
    return (off >= 0) ? v : (half8)0;
}

// ---------------------------------------------------------------- K0: W -> bf16
__global__ __launch_bounds__(256) void wconv_kernel(const float* __restrict__ w,
                                                    unsigned short* __restrict__ wbf) {
    const int idx8 = (blockIdx.x * 256 + threadIdx.x) * 8;
    const float4 v0 = *reinterpret_cast<const float4*>(w + idx8);
    const float4 v1 = *reinterpret_cast<const float4*>(w + idx8 + 4);
    uint4 o;
    o.x = pack2bf(v0.x, v0.y);
    o.y = pack2bf(v0.z, v0.w);
    o.z = pack2bf(v1.x, v1.y);
    o.w = pack2bf(v1.z, v1.w);
    *reinterpret_cast<uint4*>(wbf + idx8) = o;
}

// ------------------------------------------------- K1: dilated conv cascade + gating
// 512 threads; thread t owns [t*8, t*8+8) as half8. Levels 0-2 (dil 1/2/4) are
// computed ENTIRELY IN REGISTERS from a redundant x-window (5 blocks, zero-clamped)
// via static shufflevector mixes -> 3 fewer LDS write/barrier/read rounds.
// Levels 3-9 use double-buffered f16 LDS (1 barrier/level); lev10 a-conv only.
// Gate fully f16-packed (h2exp2/h2rcp).
__global__ __launch_bounds__(512) void conv_cascade_kernel(const float* __restrict__ x,
                                                           const float* __restrict__ h0,
                                                           const float* __restrict__ h1,
                                                           unsigned short* __restrict__ ybf) {
    __shared__ _Float16 a_sh[2][CBUF];  // 28672 B
    const int row = blockIdx.x;         // b*ND + d
    const int d = row & (ND - 1);
    const int t = threadIdx.x;

    // zero both pads (never written again)
    if (t < CPAD / 8) {
        *reinterpret_cast<half8*>(&a_sh[0][t * 8]) = (half8)0;
        *reinterpret_cast<half8*>(&a_sh[1][t * 8]) = (half8)0;
    }

    const float* xrow = x + (size_t)row * NL;

    _Float16 h0c[NFS], h1c[NFS];
#pragma unroll
    for (int k = 0; k < NFS; ++k) {
        h0c[k] = (_Float16)h0[d * NFS + k];
        h1c[k] = (_Float16)h1[d * NFS + k];
    }

    const int l8 = t * 8;
    const int A = CPAD + l8;

    // x window: [l8-32, l8+8) as 5 half8 blocks (zero-clamped at row start)
    const half8 X0 = ldx8z(xrow, l8 - 32);
    const half8 X1 = ldx8z(xrow, l8 - 24);
    const half8 X2 = ldx8z(xrow, l8 - 16);
    const half8 X3 = ldx8z(xrow, l8 - 8);
    const half8 C  = ldx8(xrow + l8);

    const __half2 nlog2e = __float2half2_rn(-1.44269504f);
    const __half2 one2 = __float2half2_rn(1.f);
    const __half2 two2 = __float2half2_rn(2.f);
    __half2 yacc2[4];
#pragma unroll
    for (int p = 0; p < 4; ++p) yacc2[p] = __float2half2_rn(0.f);

// shifted view: element j of result = position (blockstart + j - s); L covers -8..0
#define SH1(L, R) __builtin_shufflevector(L, R, 7, 8, 9, 10, 11, 12, 13, 14)
#define SH2(L, R) __builtin_shufflevector(L, R, 6, 7, 8, 9, 10, 11, 12, 13)
#define SH3(L, R) __builtin_shufflevector(L, R, 5, 6, 7, 8, 9, 10, 11, 12)
#define SH4(L, R) __builtin_shufflevector(L, R, 4, 5, 6, 7, 8, 9, 10, 11)
#define SH6(L, R) __builtin_shufflevector(L, R, 2, 3, 4, 5, 6, 7, 8, 9)
// dil=1 conv (lags 1,2,3) and dil=2 conv (lags 2,4,6)
#define CONV_D1(L, R, hc) ((R)*hc[3] + SH1(L, R) * hc[2] + SH2(L, R) * hc[1] + SH3(L, R) * hc[0])
#define CONV_D2(L, R, hc) ((R)*hc[3] + SH2(L, R) * hc[2] + SH4(L, R) * hc[1] + SH6(L, R) * hc[0])

// yacc += SC2 * sigmoid(av) * bv, fully packed f16
#define GATE(av, bv, SC2)                                           \
    {                                                               \
        __half2 ap_[4], bp_[4];                                     \
        __builtin_memcpy(ap_, &(av), 16);                           \
        __builtin_memcpy(bp_, &(bv), 16);                           \
        _Pragma("unroll") for (int p = 0; p < 4; ++p) {             \
            const __half2 e = h2exp2(__hmul2(ap_[p], nlog2e));      \
            const __half2 s = h2rcp(__hadd2(e, one2));              \
            const __half2 g = __hmul2(__hmul2(s, bp_[p]), SC2);     \
            yacc2[p] = __hadd2(g, yacc2[p]);                        \
        }                                                           \
    }

    // ---- lev 0 (dil=1), register-only: a0 on 4 blocks, b0 own
    const half8 a0_1 = CONV_D1(X0, X1, h0c);
    const half8 a0_2 = CONV_D1(X1, X2, h0c);
    const half8 a0_3 = CONV_D1(X2, X3, h0c);
    const half8 a0_4 = CONV_D1(X3, C, h0c);
    const half8 b0 = CONV_D1(X3, C, h1c);

    // ---- lev 1 (dil=2), register-only: a1 on 3 blocks, b1 own; gate x2
    const half8 a1_2 = CONV_D2(a0_1, a0_2, h0c);
    const half8 a1_3 = CONV_D2(a0_2, a0_3, h0c);
    const half8 a1_4 = CONV_D2(a0_3, a0_4, h0c);
    const half8 b1 = CONV_D2(a0_3, a0_4, h1c);
    GATE(a1_4, b0, two2)

    // ---- lev 2 (dil=4), register-only (lags 4,8,12); gate
    const half8 s4 = SH4(a1_3, a1_4);
    const half8 s12 = SH4(a1_2, a1_3);
    const half8 a2 = a1_4 * h0c[3] + s4 * h0c[2] + a1_3 * h0c[1] + s12 * h0c[0];
    const half8 b2 = a1_4 * h1c[3] + s4 * h1c[2] + a1_3 * h1c[1] + s12 * h1c[0];
    GATE(a2, b1, one2)

    half8 cur = a2;
    half8 bprev = b2;
    _Float16* rbp = &a_sh[0][0];
    _Float16* wbp = &a_sh[1][0];
    *reinterpret_cast<half8*>(&rbp[A]) = cur;  // publish a2
    __syncthreads();

    half8 an, bn;
#define CMATH(a1v, a2v, a3v)                                              \
    an = cur * h0c[3] + (a1v)*h0c[2] + (a2v)*h0c[1] + (a3v)*h0c[0];       \
    bn = cur * h1c[3] + (a1v)*h1c[2] + (a2v)*h1c[1] + (a3v)*h1c[0];
#define CFIN()                                                            \
    {                                                                     \
        *reinterpret_cast<half8*>(&wbp[A]) = an;                          \
        cur = an;                                                         \
        bprev = bn;                                                       \
        _Float16* tmpp = rbp; rbp = wbp; wbp = tmpp;                      \
    }

    // ---- lev 3..9 (dil=8..512): 3 direct aligned half8 reads, dbuf, 1 barrier/level
    int dil = 8;
#pragma unroll 1
    for (int lev = 3; lev <= 9; ++lev) {
        const half8 a1v = *reinterpret_cast<const half8*>(&rbp[A - dil]);
        const half8 a2v = *reinterpret_cast<const half8*>(&rbp[A - 2 * dil]);
        const half8 a3v = *reinterpret_cast<const half8*>(&rbp[A - 3 * dil]);
        CMATH(a1v, a2v, a3v)
        GATE(an, bprev, one2)
        CFIN()
        dil <<= 1;
        __syncthreads();
    }

    // ---- lev 10 (dil=1024): a-conv only (b_list[10] dead), no write-back
    {
        const half8 a1v = *reinterpret_cast<const half8*>(&rbp[A - 1024]);
        const half8 a2v = *reinterpret_cast<const half8*>(&rbp[A - 2048]);
        const half8 a3v = *reinterpret_cast<const half8*>(&rbp[A - 3072]);
        an = cur * h0c[3] + a1v * h0c[2] + a2v * h0c[1] + a3v * h0c[0];
        GATE(an, bprev, one2)
    }
#undef CMATH
#undef GATE
#undef CFIN
#undef CONV_D1
#undef CONV_D2
#undef SH1
#undef SH2
#undef SH3
#undef SH4
#undef SH6

    const float2 f0 = __half22float2(yacc2[0]);
    const float2 f1 = __half22float2(yacc2[1]);
    const float2 f2 = __half22float2(yacc2[2]);
    const float2 f3 = __half22float2(yacc2[3]);
    uint4 o;
    o.x = pack2bf(f0.x, f0.y);
    o.y = pack2bf(f1.x, f1.y);
    o.z = pack2bf(f2.x, f2.y);
    o.w = pack2bf(f3.x, f3.y);
    *reinterpret_cast<uint4*>(ybf + (size_t)row * NL + t * 8) = o;
}

// ------------------------------------------- K2: y [b][c][l] bf16 -> yT [b][l][c] bf16
__global__ __launch_bounds__(256) void transpose_kernel(const unsigned short* __restrict__ ybf,
                                                        unsigned short* __restrict__ yT) {
    __shared__ unsigned short tile[64][66];
    const int l0 = blockIdx.x * 64;
    const int c0 = blockIdx.y * 64;
    const int b = blockIdx.z;
    const int t = threadIdx.x;
    const int li = t & 63, cg = t >> 6;
#pragma unroll
    for (int k = 0; k < 16; ++k) {
        const int ci = cg * 16 + k;
        tile[ci][li] = ybf[(size_t)(b * ND + c0 + ci) * NL + l0 + li];
    }
    __syncthreads();
    const int ci2 = t & 63, lg = t >> 6;
#pragma unroll
    for (int k = 0; k < 16; ++k) {
        const int li2 = lg * 16 + k;
        yT[((size_t)b * NL + l0 + li2) * ND + c0 + ci2] = tile[ci2][li2];
    }
}

// --------------------------- K3: mixed[b][o][l] = bf16( (W @ y)[o][l] + b_mix[o] )
// ring-3 LDS staging, counted vmcnt(4); XCD-chunked block swizzle.
__global__ __launch_bounds__(256) void gemm_kernel(const unsigned short* __restrict__ wbf,
                                                   const unsigned short* __restrict__ yT,
                                                   const float* __restrict__ bmix,
                                                   unsigned short* __restrict__ mixed) {
    __shared__ unsigned short As[3][BM][BK];  // 24 KiB
    __shared__ unsigned short Bs[3][BN][BK];  // 24 KiB

    // XCD swizzle: 512 blocks, 8 XCDs, 64 per XCD (512%8==0 -> bijective)
    const int orig = blockIdx.x;
    const int wgid = (orig & 7) * 64 + (orig >> 3);
    const int b = wgid & 1;
    const int m0 = ((wgid >> 1) & 7) * BM;
    const int n0 = (wgid >> 4) * BN;

    const int t = threadIdx.x;
    const int lane = t & 63, wid = t >> 6;
    const int wr = wid >> 1, wc = wid & 1;  // 2x2 waves, each 64x64
    const int fr = lane & 15;
    const int fk = (lane >> 4) * 8;

    const int srow = wid * 32 + (lane >> 2);
    const int sk = (lane & 3) * 8;
    const unsigned short* Ag = wbf + (size_t)(m0 + srow) * ND + sk;
    const unsigned short* Bg = yT + ((size_t)b * NL + n0 + srow) * ND + sk;
    unsigned short* A0 = &As[0][0][0];
    unsigned short* B0 = &Bs[0][0][0];
    unsigned short* AsW = A0 + wid * 32 * BK;
    unsigned short* BsW = B0 + wid * 32 * BK;

#define STAGE(bo, kt)                           \
    llds16(Ag + (kt), AsW + (bo));              \
    llds16(Ag + (kt) + 16 * ND, AsW + (bo) + 16 * BK); \
    llds16(Bg + (kt), BsW + (bo));              \
    llds16(Bg + (kt) + 16 * ND, BsW + (bo) + 16 * BK);

    f32x4 acc[4][4];
#pragma unroll
    for (int mi = 0; mi < 4; ++mi)
#pragma unroll
        for (int ni = 0; ni < 4; ++ni)
            acc[mi][ni] = (f32x4){0.f, 0.f, 0.f, 0.f};

    // prologue: stage tiles 0,1 into bufs 0,1 (8 loads outstanding)
    STAGE(0, 0)
    STAGE(ASZ, BK)

    int bc = 0;   // compute buffer index
    int bs = 2;   // stage buffer index
#pragma unroll 1
    for (int ki = 0; ki < NKI; ++ki) {
        if (ki + 1 < NKI) {
            asm volatile("s_waitcnt vmcnt(4)" ::: "memory");  // tile ki landed
        } else {
            asm volatile("s_waitcnt vmcnt(0)" ::: "memory");
        }
        __builtin_amdgcn_s_barrier();
        __builtin_amdgcn_sched_barrier(0);

        if (ki + 2 < NKI) {
            const int bo = bs * ASZ;
            const int kt = (ki + 2) * BK;
            STAGE(bo, kt)
        }

        const int bco = bc * ASZ;
        bf16x8 af[4], bv[4];
#pragma unroll
        for (int mi = 0; mi < 4; ++mi)
            af[mi] = *reinterpret_cast<const bf16x8*>(A0 + bco + (wr * 64 + mi * 16 + fr) * BK + fk);
#pragma unroll
        for (int ni = 0; ni < 4; ++ni)
            bv[ni] = *reinterpret_cast<const bf16x8*>(B0 + bco + (wc * 64 + ni * 16 + fr) * BK + fk);
#pragma unroll
        for (int mi = 0; mi < 4; ++mi)
#pragma unroll
            for (int ni = 0; ni < 4; ++ni)
                acc[mi][ni] = __builtin_amdgcn_mfma_f32_16x16x32_bf16(af[mi], bv[ni],
                                                                      acc[mi][ni], 0, 0, 0);
        bc = (bc == 2) ? 0 : bc + 1;
        bs = (bs == 2) ? 0 : bs + 1;
    }
#undef STAGE

    // epilogue: D[row][col], col = lane&15, row = (lane>>4)*4 + r
    const size_t bbase = (size_t)b * ND * NL;
#pragma unroll
    for (int mi = 0; mi < 4; ++mi) {
#pragma unroll
        for (int r = 0; r < 4; ++r) {
            const int o = m0 + wr * 64 + mi * 16 + (lane >> 4) * 4 + r;
            const float bm = bmix[o];
            const size_t rowbase = bbase + (size_t)o * NL;
#pragma unroll
            for (int ni = 0; ni < 4; ++ni) {
                const int l = n0 + wc * 64 + ni * 16 + fr;
                mixed[rowbase + l] = f2bf(acc[mi][ni][r] + bm);
            }
        }
    }
}

// ------------------------- K4: z = mixed + x (regs) -> LayerNorm over channels -> out
// 1024 threads (16 waves) per block: 32 l-cols x 32 c-groups, zv[32] in registers.
__global__ __launch_bounds__(1024) void ln_kernel(const unsigned short* __restrict__ mixed,
                                                  const float* __restrict__ x,
                                                  const float* __restrict__ gamma,
                                                  const float* __restrict__ beta,
                                                  float* __restrict__ out) {
    __shared__ float gsh[ND], bsh[ND];          // 8 KiB
    __shared__ float sred[32][33], qred[32][33]; // 8.25 KiB
    __shared__ float mu_s[32], rs_s[32];

    const int t = threadIdx.x;
    gsh[t] = gamma[t];
    bsh[t] = beta[t];

    const int b = blockIdx.y;
    const int l0 = blockIdx.x * 32;
    const int tl = t & 31, tg = t >> 5;  // 32 c-groups x 32 cols
    const size_t base = (size_t)b * ND * NL + l0 + tl;

    float zv[32];
    float s = 0.f, q = 0.f;
#pragma unroll
    for (int j = 0; j < 32; ++j) {
        const size_t idx = base + (size_t)(tg + j * 32) * NL;
        const float v = bf2f(mixed[idx]) + x[idx];
        zv[j] = v;
        s += v;
        q += v * v;
    }

    sred[tg][tl] = s;
    qred[tg][tl] = q;
    __syncthreads();  // also covers gsh/bsh writes
    if (tg == 0) {
        float S = 0.f, Q = 0.f;
#pragma unroll
        for (int g = 0; g < 32; ++g) {
            S += sred[g][tl];
            Q += qred[g][tl];
        }
        const float mu = S * (1.f / ND);
        const float var = Q * (1.f / ND) - mu * mu;
        mu_s[tl] = mu;
        rs_s[tl] = rsqrtf(var + LN_EPS);
    }
    __syncthreads();
    const float mu = mu_s[tl], rs = rs_s[tl];
#pragma unroll
    for (int j = 0; j < 32; ++j) {
        const int c = tg + j * 32;
        out[base + (size_t)c * NL] = (zv[j] - mu) * rs * gsh[c] + bsh[c];
    }
}

extern "C" void kernel_launch(void* const* d_in, const int* in_sizes, int n_in,
                              void* d_out, int out_size, void* d_ws, size_t ws_size,
                              hipStream_t stream) {
    (void)in_sizes; (void)n_in; (void)out_size; (void)ws_size;
    const float* x = (const float*)d_in[0];
    const float* h0 = (const float*)d_in[1];
    const float* h1 = (const float*)d_in[2];
    const float* wmix = (const float*)d_in[3];
    const float* bmix = (const float*)d_in[4];
    const float* gamma = (const float*)d_in[5];
    const float* beta = (const float*)d_in[6];
    float* out = (float*)d_out;

    char* ws = (char*)d_ws;
    unsigned short* ybf = (unsigned short*)(ws);                              // 16 MiB
    unsigned short* yT = (unsigned short*)(ws + (size_t)16 * 1024 * 1024);    // 16 MiB
    unsigned short* wbf = (unsigned short*)(ws + (size_t)32 * 1024 * 1024);   // 2 MiB
    unsigned short* mixed = (unsigned short*)(ws + (size_t)34 * 1024 * 1024); // 16 MiB

    wconv_kernel<<<dim3(ND * ND / (256 * 8)), 256, 0, stream>>>(wmix, wbf);
    conv_cascade_kernel<<<dim3(NB * ND), 512, 0, stream>>>(x, h0, h1, ybf);
    transpose_kernel<<<dim3(NL / 64, ND / 64, NB), 256, 0, stream>>>(ybf, yT);
    gemm_kernel<<<dim3(512), 256, 0, stream>>>(wbf, yT, bmix, mixed);
    ln_kernel<<<dim3(NL / 32, NB), 1024, 0, stream>>>(mixed, x, gamma, beta, out);
}